// Round 12
// baseline (207.270 us; speedup 1.0000x reference)
//
#include <hip/hip_runtime.h>
#include <math.h>

#ifndef __has_builtin
#define __has_builtin(x) 0
#endif

#if __has_builtin(__builtin_amdgcn_rcpf)
#define FAST_RCP(x) __builtin_amdgcn_rcpf(x)
#else
#define FAST_RCP(x) (1.0f / (x))
#endif

#if __has_builtin(__builtin_amdgcn_exp2f)
#define FAST_EXP2(x) __builtin_amdgcn_exp2f(x)
#else
#define FAST_EXP2(x) exp2f(x)
#endif

typedef _Float16 half8 __attribute__((ext_vector_type(8)));
typedef _Float16 half4v __attribute__((ext_vector_type(4)));
typedef float f32x4 __attribute__((ext_vector_type(4)));

constexpr int T_STEPS  = 180;
constexpr int I_DIM    = 7;
constexpr int XLEN     = T_STEPS * I_DIM;  // 1260
constexpr int HDIM     = 64;
constexpr int BT       = 16;    // batch tile per block
constexpr int BSTRIDE  = 104;   // halfs per B row: 208 B (96 data + 8 pad)

// Block = 256 threads = 4 waves; wave w owns row-tiles {4w..4w+3} (64 of 256
// gate rows). ONE set of B-fragment reads (3 x b128) feeds 12 MFMAs and 4
// cells/thread (DS per CU-step halved vs 2-cell config; 4 independent cell
// chains give intra-wave ILP). Grid 512 -> 2 blocks/CU (anti-phased barriers,
// 8 waves/CU). Barrier domain = 4 waves (minimal convoy skew).
// Per step GEMM: gates[256 x 16] = W_aug[256 x 96(f16)] . v[96 x 16(f16)],
//   v = [x_t(7), 1, h_{t-1}(64), pad].
// A rows packed UNIT-MAJOR, adjacent-unit remap: lane (q,n15) of wave w's
// tile pt holds i,f,g,o of unit 16w+4q+pt -> thread's 4 cells are adjacent
// units {16w+4q..+3}: ONE ds_write_b64 h write per step.
// Activation scales folded into weights (exp2-ready pre-activations).
// Cell math: shared-denominator, INDEPENDENT per-cell chains (5 exp2 + 2 rcp
// per cell). x path: waves 0-1, coalesced 128-lane dword loads, 2-step-deep
// register pipeline. cs clamp upper-only (negative exp2 underflow exact).
__global__ __launch_bounds__(256, 2) void lstm_mfma_kernel(
    const float* __restrict__ x,
    const float* __restrict__ W_ih,
    const float* __restrict__ W_hh,
    const float* __restrict__ b_ih,
    const float* __restrict__ b_hh,
    const float* __restrict__ W_fc,
    const float* __restrict__ b_fc,
    float* __restrict__ out) {
    __shared__ alignas(16) _Float16 Blds[2][BT][BSTRIDE];
    __shared__ alignas(16) float hlds[BT][72];   // fp32 h_T (72: 16B rows)

    const int tid  = (int)threadIdx.x;
    const int w    = tid >> 6;    // wave 0..3
    const int lane = tid & 63;
    const int q    = lane >> 4;   // quad 0..3
    const int n15  = lane & 15;   // batch col within tile
    const long bbase = (long)blockIdx.x * BT;

    // ---- A fragments, scale-folded, in registers for all 180 steps ----
    half8 afrag[4][3];
#pragma unroll
    for (int pt = 0; pt < 4; ++pt) {
        const int rq   = n15 >> 2;             // row-quad of this packed row
        const int gate = n15 & 3;
        const int unit = 16 * w + 4 * rq + pt; // adjacent-unit remap
        const int grow = gate * HDIM + unit;   // row in PyTorch [4H, *] params
        const float scl = (gate == 2) ? 2.88539008177792681472f
                                      : -1.44269504088896340736f;
#pragma unroll
        for (int kc = 0; kc < 3; ++kc) {
#pragma unroll
            for (int j = 0; j < 8; ++j) {
                const int k = kc * 32 + q * 8 + j;
                float v;
                if (k < I_DIM)            v = W_ih[grow * I_DIM + k];
                else if (k == I_DIM)      v = b_ih[grow] + b_hh[grow];
                else if (k < 8 + HDIM)    v = W_hh[grow * HDIM + (k - 8)];
                else                      v = 0.0f;
                afrag[pt][kc][j] = (_Float16)(scl * v);
            }
        }
    }

    // ---- init both B buffers: bias col = 1, h = 0, pad = 0; buf0 x = x_0 ----
    for (int idx = tid; idx < 2 * BT * BSTRIDE; idx += 256) {
        const int buf = idx / (BT * BSTRIDE);
        const int rem = idx % (BT * BSTRIDE);
        const int n = rem / BSTRIDE, k = rem % BSTRIDE;
        float v = 0.0f;
        if (k == I_DIM)                 v = 1.0f;
        else if (k < I_DIM && buf == 0) v = x[(bbase + n) * XLEN + k];
        Blds[buf][n][k] = (_Float16)v;
    }
    __syncthreads();

    // cell ownership: units u0 = 16w+4q .. +3 (adjacent), batch n15
    const int u0 = 16 * w + 4 * q;

    // hoisted LDS pointers (loop-invariant)
    const _Float16* const rb0 = &Blds[0][n15][q * 8];
    const _Float16* const rb1 = &Blds[1][n15][q * 8];
    half4v* const hw0 = (half4v*)&Blds[0][n15][8 + u0];
    half4v* const hw1 = (half4v*)&Blds[1][n15][8 + u0];

    // x prefetch lanes: threads 0..127 (waves 0,1), n = tid>>3, i = tid&7.
    // Lane i==7 loads a dup column and stores to a dead pad column.
    const int xn = tid >> 3, xi7 = tid & 7;
    const int xi_ld = (xi7 < I_DIM) ? xi7 : I_DIM - 1;
    const int xi_st = (xi7 < I_DIM) ? xi7 : 96 + (xn & 7);
    const bool xact = (tid < 128);              // wave-uniform
    const float* const xcol = x + (bbase + xn) * XLEN + xi_ld;
    _Float16* const xw0 = &Blds[0][xn][xi_st];
    _Float16* const xw1 = &Blds[1][xn][xi_st];

    // 2-deep x pipeline
    float xA = xact ? xcol[1 * I_DIM] : 0.0f;   // x_1 (written during t=0)
    float xB = xact ? xcol[2 * I_DIM] : 0.0f;   // x_2 (written during t=1)

    float c0 = 0.0f, c1 = 0.0f, c2 = 0.0f, c3 = 0.0f;
    float h0 = 0.0f, h1 = 0.0f, h2 = 0.0f, h3 = 0.0f;

    // cell: acc = {i',f',g',o'} exp2-ready.  A=2^i', F=2^f', E=2^g', O=2^o'
    //   c' = (c*P + (E-1)*Q) * rcp(P*Q),  P=(1+A)(E+1), Q=1+F
    //   h  = (C-1) * rcp((1+O)(C+1)),     C=2^(k*c'), upper-clamped only.
#define LSTM_CELL(ACC, CREG, HREG)                                             \
    {                                                                          \
        const float A = FAST_EXP2(ACC[0]);                                     \
        const float F = FAST_EXP2(ACC[1]);                                     \
        const float E = FAST_EXP2(ACC[2]);                                     \
        const float P = (1.0f + A) * (E + 1.0f);                               \
        const float Q = 1.0f + F;                                              \
        const float R = FAST_RCP(P * Q);                                       \
        CREG = (CREG * P + (E - 1.0f) * Q) * R;                                \
        const float O = FAST_EXP2(ACC[3]);                                     \
        const float cs = fminf(2.88539008177792681472f * CREG, 126.0f);        \
        const float C = FAST_EXP2(cs);                                         \
        HREG = (C - 1.0f) * FAST_RCP((1.0f + O) * (C + 1.0f));                 \
    }

#define LSTM_STEP(TT, RB, HW, XW, XREG)                                        \
    {                                                                          \
        const half8 bf0 = *(const half8*)(RB);                                 \
        const half8 bf1 = *(const half8*)((RB) + 32);                          \
        const half8 bf2 = *(const half8*)((RB) + 64);                          \
        if (xact) {                                                            \
            *(XW) = (_Float16)XREG;                                            \
            int tl = (TT) + 3;                                                 \
            if (tl >= T_STEPS) tl = T_STEPS - 1;                               \
            XREG = xcol[tl * I_DIM];                                           \
        }                                                                      \
        f32x4 acc0 = {0.f, 0.f, 0.f, 0.f};                                     \
        f32x4 acc1 = {0.f, 0.f, 0.f, 0.f};                                     \
        f32x4 acc2 = {0.f, 0.f, 0.f, 0.f};                                     \
        f32x4 acc3 = {0.f, 0.f, 0.f, 0.f};                                     \
        acc0 = __builtin_amdgcn_mfma_f32_16x16x32_f16(afrag[0][0], bf0, acc0, 0, 0, 0); \
        acc1 = __builtin_amdgcn_mfma_f32_16x16x32_f16(afrag[1][0], bf0, acc1, 0, 0, 0); \
        acc2 = __builtin_amdgcn_mfma_f32_16x16x32_f16(afrag[2][0], bf0, acc2, 0, 0, 0); \
        acc3 = __builtin_amdgcn_mfma_f32_16x16x32_f16(afrag[3][0], bf0, acc3, 0, 0, 0); \
        acc0 = __builtin_amdgcn_mfma_f32_16x16x32_f16(afrag[0][1], bf1, acc0, 0, 0, 0); \
        acc1 = __builtin_amdgcn_mfma_f32_16x16x32_f16(afrag[1][1], bf1, acc1, 0, 0, 0); \
        acc2 = __builtin_amdgcn_mfma_f32_16x16x32_f16(afrag[2][1], bf1, acc2, 0, 0, 0); \
        acc3 = __builtin_amdgcn_mfma_f32_16x16x32_f16(afrag[3][1], bf1, acc3, 0, 0, 0); \
        acc0 = __builtin_amdgcn_mfma_f32_16x16x32_f16(afrag[0][2], bf2, acc0, 0, 0, 0); \
        acc1 = __builtin_amdgcn_mfma_f32_16x16x32_f16(afrag[1][2], bf2, acc1, 0, 0, 0); \
        acc2 = __builtin_amdgcn_mfma_f32_16x16x32_f16(afrag[2][2], bf2, acc2, 0, 0, 0); \
        acc3 = __builtin_amdgcn_mfma_f32_16x16x32_f16(afrag[3][2], bf2, acc3, 0, 0, 0); \
        LSTM_CELL(acc0, c0, h0)                                                \
        LSTM_CELL(acc1, c1, h1)                                                \
        LSTM_CELL(acc2, c2, h2)                                                \
        LSTM_CELL(acc3, c3, h3)                                                \
        *(HW) = (half4v){(_Float16)h0, (_Float16)h1,                           \
                         (_Float16)h2, (_Float16)h3};                          \
        __syncthreads();                                                       \
    }

    for (int t = 0; t < T_STEPS; t += 2) {
        LSTM_STEP(t, rb0, hw1, xw1, xA)       // read buf0, write buf1
        LSTM_STEP(t + 1, rb1, hw0, xw0, xB)   // read buf1, write buf0
    }
#undef LSTM_STEP
#undef LSTM_CELL

    // ---- epilogue: out[b][j] = b_fc[j] + sum_u h[b][u] * W_fc[j][u] ----
    *(f32x4*)&hlds[n15][u0] = (f32x4){h0, h1, h2, h3};
    __syncthreads();
    {
        const int b = tid >> 4, j = tid & 15;   // 256 threads = 16x16
        float s = b_fc[j];
#pragma unroll 8
        for (int u = 0; u < HDIM; ++u)
            s += hlds[b][u] * W_fc[j * HDIM + u];
        out[(bbase + b) * 16 + j] = s;
    }
}

extern "C" void kernel_launch(void* const* d_in, const int* in_sizes, int n_in,
                              void* d_out, int out_size, void* d_ws, size_t ws_size,
                              hipStream_t stream) {
    const float* x    = (const float*)d_in[0];
    const float* W_ih = (const float*)d_in[1];
    const float* W_hh = (const float*)d_in[2];
    const float* b_ih = (const float*)d_in[3];
    const float* b_hh = (const float*)d_in[4];
    const float* W_fc = (const float*)d_in[5];
    const float* b_fc = (const float*)d_in[6];
    float* out = (float*)d_out;

    const int B = in_sizes[0] / XLEN;   // 8192
    const int grid = B / BT;            // 512 blocks = 2 per CU

    lstm_mfma_kernel<<<grid, 256, 0, stream>>>(x, W_ih, W_hh, b_ih, b_hh,
                                               W_fc, b_fc, out);
}